// Round 3
// baseline (267.569 us; speedup 1.0000x reference)
//
#include <hip/hip_runtime.h>
#include <math.h>

#define IMG_H 512
#define IMG_W 512
#define NIMG 96            // 32 * 3
#define BH 64              // output rows per band
#define NBANDS 8           // 512 / 64
#define ROWS_IN (BH + 10)  // 74 streamed input rows per band
#define NCHUNK 7           // 7*11 = 77 >= 74
#define SSTR 528           // staged row stride (floats), 524 used
#define HOFF 6             // left halo offset (even -> 8B-aligned writes)

// Each thread owns 2 adjacent columns; block (256 thr) covers full 512-col row.
// Per row: stage p,t row in LDS (double-buffered, 1 barrier), horizontal 11-tap
// conv of {p, t, p^2, t^2, p*t} into an 11-deep register rolling buffer
// (statically indexed via unroll-by-11), then vertical 11-tap + SSIM.
__global__ __launch_bounds__(256, 2)
void ssim_main(const float* __restrict__ Pg, const float* __restrict__ Tg,
               float* __restrict__ acc) {
    __shared__ float sP[2 * SSTR];
    __shared__ float sT[2 * SSTR];
    __shared__ float wavesum[4];

    const int t = threadIdx.x;
    const int R0 = blockIdx.x * BH;
    const size_t plane = (size_t)blockIdx.y * (IMG_H * IMG_W);
    const float* P = Pg + plane;
    const float* T = Tg + plane;

    // Gaussian weights: sigma=1.5, K=11, normalized (matches reference).
    // Arguments are compile-time constants -> clang constant-folds expf.
    float w[11];
    {
        float s = 0.f;
#pragma unroll
        for (int k = 0; k < 11; ++k) {
            const float d = (float)(k - 5);
            w[k] = expf(-d * d / 4.5f);
            s += w[k];
        }
        const float inv = 1.0f / s;
#pragma unroll
        for (int k = 0; k < 11; ++k) w[k] *= inv;
    }

    // Zero the halo slots once (cols -6..-1 and 512..517); first in-loop
    // __syncthreads orders these before any read.
    if (t < 6) {
#pragma unroll
        for (int b = 0; b < 2; ++b) {
            sP[b * SSTR + t] = 0.f;
            sT[b * SSTR + t] = 0.f;
            sP[b * SSTR + 518 + t] = 0.f;
            sT[b * SSTR + 518 + t] = 0.f;
        }
    }

    // Prefetch input row for li = 0 (global row R0 - 5).
    float2 pv = {0.f, 0.f}, tv = {0.f, 0.f};
    {
        const int gr0 = R0 - 5;
        if (gr0 >= 0) {
            pv = *(const float2*)(P + (size_t)gr0 * IMG_W + 2 * t);
            tv = *(const float2*)(T + (size_t)gr0 * IMG_W + 2 * t);
        }
    }

    // Rolling buffers: 5 maps x 2 cols x 11 rows. All indexing is static.
    float bP[2][11], bT[2][11], bPP[2][11], bTT[2][11], bPT[2][11];
    float ssum = 0.f;

    for (int j = 0; j < NCHUNK; ++j) {
#pragma unroll
        for (int s = 0; s < 11; ++s) {
            const int li = 11 * j + s;   // uniform across block
            if (li < ROWS_IN) {
                float* SPb = sP + (li & 1) * SSTR;
                float* STb = sT + (li & 1) * SSTR;
                *(float2*)(SPb + HOFF + 2 * t) = pv;
                *(float2*)(STb + HOFF + 2 * t) = tv;

                // Prefetch the next row (hides HBM latency under this row's math).
                {
                    const int grn = R0 - 5 + li + 1;
                    float2 np = {0.f, 0.f}, nt = {0.f, 0.f};
                    if (li + 1 < ROWS_IN && grn >= 0 && grn < IMG_H) {
                        np = *(const float2*)(P + (size_t)grn * IMG_W + 2 * t);
                        nt = *(const float2*)(T + (size_t)grn * IMG_W + 2 * t);
                    }
                    pv = np; tv = nt;
                }

                __syncthreads();

                // Read the 14-float window (8B-aligned) covering cols 2t-6 .. 2t+7.
                float p[14], q[14];
#pragma unroll
                for (int k = 0; k < 7; ++k) {
                    const float2 a = *(const float2*)(SPb + 2 * t + 2 * k);
                    const float2 b = *(const float2*)(STb + 2 * t + 2 * k);
                    p[2 * k] = a.x; p[2 * k + 1] = a.y;
                    q[2 * k] = b.x; q[2 * k + 1] = b.y;
                }

                // Horizontal 11-tap conv of 5 maps for both columns.
                // Window for col0 (c=2t): indices 1..11; col1: 2..12.
                float h00 = 0, h01 = 0, h02 = 0, h03 = 0, h04 = 0;
                float h10 = 0, h11 = 0, h12 = 0, h13 = 0, h14 = 0;
#pragma unroll
                for (int i = 1; i <= 12; ++i) {
                    const float ppv = p[i] * p[i];
                    const float ttv = q[i] * q[i];
                    const float ptv = p[i] * q[i];
                    if (i <= 11) {
                        const float wk = w[i - 1];
                        h00 = fmaf(wk, p[i], h00);
                        h01 = fmaf(wk, q[i], h01);
                        h02 = fmaf(wk, ppv, h02);
                        h03 = fmaf(wk, ttv, h03);
                        h04 = fmaf(wk, ptv, h04);
                    }
                    if (i >= 2) {
                        const float wk = w[i - 2];
                        h10 = fmaf(wk, p[i], h10);
                        h11 = fmaf(wk, q[i], h11);
                        h12 = fmaf(wk, ppv, h12);
                        h13 = fmaf(wk, ttv, h13);
                        h14 = fmaf(wk, ptv, h14);
                    }
                }
                bP[0][s] = h00; bT[0][s] = h01; bPP[0][s] = h02; bTT[0][s] = h03; bPT[0][s] = h04;
                bP[1][s] = h10; bT[1][s] = h11; bPP[1][s] = h12; bTT[1][s] = h13; bPT[1][s] = h14;

                // Vertical 11-tap + SSIM once the window is full.
                if (li >= 10) {
#pragma unroll
                    for (int c = 0; c < 2; ++c) {
                        float mx = 0, my = 0, vxx = 0, vyy = 0, vxy = 0;
#pragma unroll
                        for (int k = 0; k < 11; ++k) {
                            const int sl = (s + 1 + k) % 11;  // compile-time
                            const float wk = w[k];
                            mx  = fmaf(wk, bP[c][sl],  mx);
                            my  = fmaf(wk, bT[c][sl],  my);
                            vxx = fmaf(wk, bPP[c][sl], vxx);
                            vyy = fmaf(wk, bTT[c][sl], vyy);
                            vxy = fmaf(wk, bPT[c][sl], vxy);
                        }
                        const float C1 = 4.0e-4f;   // (0.01*2)^2
                        const float C2 = 3.6e-3f;   // (0.03*2)^2
                        const float mxx = mx * mx, myy = my * my, mxy = mx * my;
                        const float sx = fmaxf(vxx - mxx, 0.f);
                        const float sy = fmaxf(vyy - myy, 0.f);
                        const float sxy = vxy - mxy;
                        const float num = fmaf(2.f, mxy, C1) * fmaf(2.f, sxy, C2);
                        const float den = (mxx + myy + C1) * (sx + sy + C2);
                        // rcp + one Newton-Raphson step: ~1 ulp at +2 FMA cost.
                        float r = __builtin_amdgcn_rcpf(den);
                        r = r * fmaf(-den, r, 2.0f);
                        ssum += num * r;
                    }
                }
            }
        }
    }

    // Reduce: wave shuffle -> per-wave LDS -> one atomic per block.
#pragma unroll
    for (int off = 32; off > 0; off >>= 1) ssum += __shfl_down(ssum, off);
    if ((t & 63) == 0) wavesum[t >> 6] = ssum;
    __syncthreads();
    if (t == 0) {
        atomicAdd(acc, wavesum[0] + wavesum[1] + wavesum[2] + wavesum[3]);
    }
}

__global__ void ssim_final(const float* __restrict__ acc, float* __restrict__ out) {
    out[0] = 1.0f - acc[0] / 25165824.0f;  // 32*3*512*512
}

extern "C" void kernel_launch(void* const* d_in, const int* in_sizes, int n_in,
                              void* d_out, int out_size, void* d_ws, size_t ws_size,
                              hipStream_t stream) {
    const float* pred = (const float*)d_in[0];
    const float* targ = (const float*)d_in[1];
    float* acc = (float*)d_ws;

    hipMemsetAsync(d_ws, 0, sizeof(float), stream);  // d_ws is re-poisoned 0xAA
    dim3 grid(NBANDS, NIMG);
    ssim_main<<<grid, 256, 0, stream>>>(pred, targ, acc);
    ssim_final<<<1, 1, 0, stream>>>(acc, (float*)d_out);
}